// Round 12
// baseline (328.292 us; speedup 1.0000x reference)
//
#include <hip/hip_runtime.h>

#define D 128
#define SCAN_EPB 1024   // counters per scan block (256 threads x int4)

typedef float f32x4 __attribute__((ext_vector_type(4)));
typedef short s16x8 __attribute__((ext_vector_type(8)));

__device__ __forceinline__ unsigned short f2bf(float f) {
    union { float f; unsigned u; } v; v.f = f;
    unsigned r = v.u + 0x7FFF + ((v.u >> 16) & 1);   // RNE
    return (unsigned short)(r >> 16);
}
__device__ __forceinline__ float bf2f(unsigned short u) {
    union { unsigned u; float f; } v; v.u = (unsigned)u << 16;
    return v.f;
}
__device__ __forceinline__ s16x8 pack2(float4 lo, float4 hi) {
    s16x8 o;
    o[0] = (short)f2bf(lo.x); o[1] = (short)f2bf(lo.y);
    o[2] = (short)f2bf(lo.z); o[3] = (short)f2bf(lo.w);
    o[4] = (short)f2bf(hi.x); o[5] = (short)f2bf(hi.y);
    o[6] = (short)f2bf(hi.z); o[7] = (short)f2bf(hi.w);
    return o;
}

// ---------------------------------------------------------------------------
// Prep: transpose weights to [col][k] bf16 once; fuse biases of A|B.
// ---------------------------------------------------------------------------
__launch_bounds__(256)
__global__ void prep_weights(const float* __restrict__ WA, const float* __restrict__ bA,
                             const float* __restrict__ WB, const float* __restrict__ bB,
                             const float* __restrict__ Wn,
                             short* __restrict__ Wab_t, short* __restrict__ Wn_t,
                             float* __restrict__ bias_ab)
{
    const int b = blockIdx.x, t = threadIdx.x;
    if (b < 256) {                                   // Wab_t col b, K=128
        if (t < 128)
            Wab_t[b * 128 + t] = (short)f2bf(b < 128 ? WA[t * 128 + b]
                                                     : WB[t * 128 + (b - 128)]);
        if (t == 128) bias_ab[b] = (b < 128) ? bA[b] : bB[b - 128];
    } else {                                         // Wn_t col (b-256), K=256
        const int col = b - 256;
        Wn_t[col * 256 + t] = (short)f2bf(Wn[t * 128 + col]);
    }
}

// ---------------------------------------------------------------------------
// Kernel 1: bf16 MFMA GEMM producing interleaved AB4 rows:
// group j (4 shorts): [a_{2j}, a_{2j+1}, b_{2j}, b_{2j+1}]  (a=h@WA+bA, b=h@WB+bB)
// so node_gather fetches a-pair + b-pair with ONE dwordx2 per edge per lane.
// ---------------------------------------------------------------------------
__launch_bounds__(256)
__global__ void gemm_ab_mfma(const float* __restrict__ h,
                             const short* __restrict__ Wab_t,
                             const float* __restrict__ bias_ab,
                             short* __restrict__ AB, int N)
{
    const int tid = threadIdx.x, w = tid >> 6, l = tid & 63;
    const int rbase = blockIdx.x * 64 + w * 16;
    if (rbase >= N) return;                          // N%16==0: waves all-or-nothing
    const int g = l >> 4, r = l & 15;

    const float* hrow = h + (size_t)(rbase + r) * D + g * 8;
    s16x8 af[4];
    #pragma unroll
    for (int s = 0; s < 4; ++s) {
        float4 lo = *(const float4*)(hrow + s * 32);
        float4 hi = *(const float4*)(hrow + s * 32 + 4);
        af[s] = pack2(lo, hi);
    }

    f32x4 acc[16];
    #pragma unroll
    for (int t = 0; t < 16; ++t) acc[t] = (f32x4){0.f, 0.f, 0.f, 0.f};

    #pragma unroll
    for (int t = 0; t < 16; ++t) {
        const short* wc = Wab_t + (size_t)(t * 16 + r) * 128 + g * 8;
        #pragma unroll
        for (int s = 0; s < 4; ++s) {
            s16x8 bf = *(const s16x8*)(wc + s * 32);
            acc[t] = __builtin_amdgcn_mfma_f32_16x16x32_bf16(af[s], bf, acc[t], 0, 0, 0);
        }
    }

    #pragma unroll
    for (int t = 0; t < 16; ++t) {
        const int col = t * 16 + r;
        const int f   = col & 127;
        const int pos = ((f >> 1) << 2) + (f & 1) + ((col < 128) ? 0 : 2);
        const float bb = bias_ab[col];
        #pragma unroll
        for (int q = 0; q < 4; ++q) {
            const int orow = rbase + g * 4 + q;
            AB[(size_t)orow * 256 + pos] = (short)f2bf(acc[t][q] + bb);
        }
    }
}

// ---------------------------------------------------------------------------
// CSR build: histogram -> 3-pass multi-block exclusive scan -> scatter
// ---------------------------------------------------------------------------
__launch_bounds__(256)
__global__ void hist_kernel(const int* __restrict__ dst,
                            int* __restrict__ counters, int E)
{
    const int e = blockIdx.x * 256 + threadIdx.x;
    if (e < E) atomicAdd(&counters[dst[e]], 1);
}

__launch_bounds__(256)
__global__ void scan_pass1(const int* __restrict__ counters,
                           int* __restrict__ block_sums, int N)
{
    const int b = blockIdx.x, t = threadIdx.x;
    const int base = b * SCAN_EPB + t * 4;
    int s = 0;
    if (base + 3 < N) {
        const int4 v = *(const int4*)&counters[base];
        s = v.x + v.y + v.z + v.w;
    } else {
        #pragma unroll
        for (int i = 0; i < 4; ++i) if (base + i < N) s += counters[base + i];
    }
    #pragma unroll
    for (int off = 32; off >= 1; off >>= 1) s += __shfl_xor(s, off);
    __shared__ int ws[4];
    const int wave = t >> 6, lane = t & 63;
    if (lane == 0) ws[wave] = s;
    __syncthreads();
    if (t == 0) block_sums[b] = ws[0] + ws[1] + ws[2] + ws[3];
}

__launch_bounds__(1024)
__global__ void scan_pass2(const int* __restrict__ block_sums,
                           int* __restrict__ block_offs, int NB)
{
    __shared__ int part[1024];
    const int t = threadIdx.x;
    part[t] = (t < NB) ? block_sums[t] : 0;
    __syncthreads();
    for (int off = 1; off < 1024; off <<= 1) {
        int v = (t >= off) ? part[t - off] : 0;
        __syncthreads();
        part[t] += v;
        __syncthreads();
    }
    if (t < NB) block_offs[t] = (t == 0) ? 0 : part[t - 1];
}

__launch_bounds__(256)
__global__ void scan_pass3(const int* __restrict__ counters,
                           const int* __restrict__ block_offs,
                           int* __restrict__ row_ptr, int* __restrict__ cursor,
                           int N, int E)
{
    const int b = blockIdx.x, t = threadIdx.x;
    const int wave = t >> 6, lane = t & 63;
    const int base = b * SCAN_EPB + t * 4;

    int4 v = make_int4(0, 0, 0, 0);
    if (base + 3 < N) {
        v = *(const int4*)&counters[base];
    } else {
        if (base + 0 < N) v.x = counters[base + 0];
        if (base + 1 < N) v.y = counters[base + 1];
        if (base + 2 < N) v.z = counters[base + 2];
        if (base + 3 < N) v.w = counters[base + 3];
    }
    const int tsum = v.x + v.y + v.z + v.w;

    int x = tsum;
    #pragma unroll
    for (int off = 1; off < 64; off <<= 1) {
        int y = __shfl_up(x, off);
        if (lane >= off) x += y;
    }
    __shared__ int wsum[4];
    if (lane == 63) wsum[wave] = x;
    __syncthreads();
    int woff = 0;
    #pragma unroll
    for (int w = 0; w < 4; ++w) woff += (w < wave) ? wsum[w] : 0;

    const int p0 = block_offs[b] + woff + (x - tsum);
    const int p1 = p0 + v.x;
    const int p2 = p1 + v.y;
    const int p3 = p2 + v.z;
    if (base + 0 < N) { row_ptr[base + 0] = p0; cursor[base + 0] = p0; }
    if (base + 1 < N) { row_ptr[base + 1] = p1; cursor[base + 1] = p1; }
    if (base + 2 < N) { row_ptr[base + 2] = p2; cursor[base + 2] = p2; }
    if (base + 3 < N) { row_ptr[base + 3] = p3; cursor[base + 3] = p3; }
    if (b == 0 && t == 0) row_ptr[N] = E;
}

__launch_bounds__(256)
__global__ void scatter_kernel(const int* __restrict__ src,
                               const int* __restrict__ dst,
                               int* __restrict__ cursor,
                               int* __restrict__ edge_src, int E)
{
    const int e = blockIdx.x * 256 + threadIdx.x;
    if (e < E) {
        const int pos = atomicAdd(&cursor[dst[e]], 1);
        edge_src[pos] = src[e];
    }
}

// ---------------------------------------------------------------------------
// Kernel 2: per-dst-node gather + gated-message max-reduce (interleaved AB4).
// Edge ids read wave-uniform (scalar pipe does row addressing); one dwordx2
// per edge per lane; 4-edge unroll with 4 independent max chains.
// m init 0 = relu + zero-in-degree clamp.
// ---------------------------------------------------------------------------
__device__ __forceinline__ void edge_step(const short* __restrict__ AB, int s,
                                          unsigned lofs8, float bd0, float bd1,
                                          float& m0, float& m1)
{
    const short* rowp = AB + ((size_t)s << 8);
    const uint2 v = *(const uint2*)((const char*)rowp + lofs8);
    const float e0 = __uint_as_float(v.y << 16) + bd0;
    const float e1 = __uint_as_float(v.y & 0xFFFF0000u) + bd1;
    const float p0 = __fdividef(__uint_as_float(v.x << 16), 1.f + __expf(-e0));
    const float p1 = __fdividef(__uint_as_float(v.x & 0xFFFF0000u), 1.f + __expf(-e1));
    m0 = fmaxf(m0, p0);
    m1 = fmaxf(m1, p1);
}

__launch_bounds__(256)
__global__ void node_gather(const short* __restrict__ AB,
                            const int* __restrict__ row_ptr,
                            const int* __restrict__ edge_src,
                            short* __restrict__ c, int N)
{
    const int wave = threadIdx.x >> 6, lane = threadIdx.x & 63;
    const int d = blockIdx.x * 4 + wave;
    if (d >= N) return;

    const int beg = __builtin_amdgcn_readfirstlane(row_ptr[d]);
    const int end = __builtin_amdgcn_readfirstlane(row_ptr[d + 1]);
    const unsigned lofs8 = (unsigned)lane * 8;       // byte offset of group j=lane

    // dst b-pair: dword at byte offset lane*8 + 4 of row d
    const unsigned bdp = *(const unsigned*)((const char*)(AB + ((size_t)d << 8)) + lofs8 + 4);
    const float bd0 = __uint_as_float(bdp << 16);
    const float bd1 = __uint_as_float(bdp & 0xFFFF0000u);

    float m0a = 0.f, m1a = 0.f, m0b = 0.f, m1b = 0.f;
    float m0c = 0.f, m1c = 0.f, m0d = 0.f, m1d = 0.f;

    int i = beg;
    for (; i + 4 <= end; i += 4) {
        const int s0 = __builtin_amdgcn_readfirstlane(edge_src[i]);
        const int s1 = __builtin_amdgcn_readfirstlane(edge_src[i + 1]);
        const int s2 = __builtin_amdgcn_readfirstlane(edge_src[i + 2]);
        const int s3 = __builtin_amdgcn_readfirstlane(edge_src[i + 3]);
        edge_step(AB, s0, lofs8, bd0, bd1, m0a, m1a);
        edge_step(AB, s1, lofs8, bd0, bd1, m0b, m1b);
        edge_step(AB, s2, lofs8, bd0, bd1, m0c, m1c);
        edge_step(AB, s3, lofs8, bd0, bd1, m0d, m1d);
    }
    for (; i < end; ++i) {
        const int s = __builtin_amdgcn_readfirstlane(edge_src[i]);
        edge_step(AB, s, lofs8, bd0, bd1, m0a, m1a);
    }

    const float m0 = fmaxf(fmaxf(m0a, m0b), fmaxf(m0c, m0d));
    const float m1 = fmaxf(fmaxf(m1a, m1b), fmaxf(m1c, m1d));
    const unsigned packed = (unsigned)f2bf(m0) | ((unsigned)f2bf(m1) << 16);
    *(unsigned*)&c[(size_t)d * D + lane * 2] = packed;
}

// ---------------------------------------------------------------------------
// Kernel 3: bundle = [h|c]@Wn + bn (bf16 MFMA, K=256); L2-norm; relu; residual.
// ---------------------------------------------------------------------------
__launch_bounds__(256)
__global__ void node_apply_mfma(const float* __restrict__ h,
                                const short* __restrict__ c,
                                const short* __restrict__ Wn_t,
                                const float* __restrict__ bn,
                                float* __restrict__ out, int N)
{
    const int tid = threadIdx.x, w = tid >> 6, l = tid & 63;
    const int rbase = blockIdx.x * 64 + w * 16;
    if (rbase >= N) return;
    const int g = l >> 4, r = l & 15;

    const float* hrow = h + (size_t)(rbase + r) * D + g * 8;
    const short* crow = c + (size_t)(rbase + r) * D + g * 8;

    f32x4 acc[8];
    #pragma unroll
    for (int t = 0; t < 8; ++t) acc[t] = (f32x4){0.f, 0.f, 0.f, 0.f};

    #pragma unroll
    for (int s = 0; s < 8; ++s) {
        s16x8 af;
        if (s < 4) {
            float4 lo = *(const float4*)(hrow + s * 32);
            float4 hi = *(const float4*)(hrow + s * 32 + 4);
            af = pack2(lo, hi);
        } else {
            af = *(const s16x8*)(crow + (s - 4) * 32);
        }
        #pragma unroll
        for (int t = 0; t < 8; ++t) {
            s16x8 bf = *(const s16x8*)(Wn_t + (size_t)(t * 16 + r) * 256 + s * 32 + g * 8);
            acc[t] = __builtin_amdgcn_mfma_f32_16x16x32_bf16(af, bf, acc[t], 0, 0, 0);
        }
    }

    float v[8][4];
    float ss[4] = {0.f, 0.f, 0.f, 0.f};
    #pragma unroll
    for (int t = 0; t < 8; ++t) {
        const float bb = bn[t * 16 + r];
        #pragma unroll
        for (int q = 0; q < 4; ++q) {
            const float x = acc[t][q] + bb;
            v[t][q] = x;
            ss[q] += x * x;
        }
    }
    #pragma unroll
    for (int m = 1; m < 16; m <<= 1) {      // reduce across the 16 lanes of a group
        #pragma unroll
        for (int q = 0; q < 4; ++q) ss[q] += __shfl_xor(ss[q], m);
    }
    float inv[4];
    #pragma unroll
    for (int q = 0; q < 4; ++q) inv[q] = 1.0f / fmaxf(sqrtf(ss[q]), 1e-12f);

    #pragma unroll
    for (int t = 0; t < 8; ++t) {
        const int col = t * 16 + r;
        #pragma unroll
        for (int q = 0; q < 4; ++q) {
            const size_t o = (size_t)(rbase + g * 4 + q) * D + col;
            out[o] = h[o] + fmaxf(v[t][q] * inv[q], 0.0f);
        }
    }
}

// ---------------------------------------------------------------------------
extern "C" void kernel_launch(void* const* d_in, const int* in_sizes, int n_in,
                              void* d_out, int out_size, void* d_ws, size_t ws_size,
                              hipStream_t stream)
{
    const float* h   = (const float*)d_in[0];
    const int*   src = (const int*)  d_in[1];
    const int*   dst = (const int*)  d_in[2];
    const float* WA  = (const float*)d_in[3];
    const float* bA  = (const float*)d_in[4];
    const float* WB  = (const float*)d_in[5];
    const float* bB  = (const float*)d_in[6];
    const float* Wn  = (const float*)d_in[7];
    const float* bn  = (const float*)d_in[8];

    const int N = in_sizes[0] / D;
    const int E = in_sizes[1];

    // workspace layout (~42 MB; rounds 6-7 prove ws >= ~55 MB)
    const size_t npad = (size_t)((N + 4 + 3) / 4) * 4;
    const size_t n4   = (size_t)((N + 3) / 4) * 4;
    short* AB         = (short*)d_ws;                 // [N][256] bf16, AB4 interleaved
    short* c_bf       = AB + (size_t)N * 256;         // [N][128] bf16
    short* Wab_t      = c_bf + (size_t)N * D;         // [256][128] bf16
    short* Wn_t       = Wab_t + 256 * 128;            // [128][256] bf16
    float* bias_ab    = (float*)(Wn_t + 128 * 256);   // [256]
    int*   row_ptr    = (int*)(bias_ab + 256);
    int*   cursor     = row_ptr + npad;
    int*   cnt_buf    = cursor + n4;
    int*   block_sums = cnt_buf + n4;
    int*   block_offs = block_sums + 1024;
    int*   edge_src   = block_offs + 1024;

    hipMemsetAsync(cnt_buf, 0, (size_t)N * sizeof(int), stream);

    prep_weights<<<384, 256, 0, stream>>>(WA, bA, WB, bB, Wn, Wab_t, Wn_t, bias_ab);

    const int gb = (N + 63) / 64;
    gemm_ab_mfma<<<gb, 256, 0, stream>>>(h, Wab_t, bias_ab, AB, N);

    const int eb = (E + 255) / 256;
    const int NB = (N + SCAN_EPB - 1) / SCAN_EPB;
    hist_kernel<<<eb, 256, 0, stream>>>(dst, cnt_buf, E);
    scan_pass1<<<NB, 256, 0, stream>>>(cnt_buf, block_sums, N);
    scan_pass2<<<1, 1024, 0, stream>>>(block_sums, block_offs, NB);
    scan_pass3<<<NB, 256, 0, stream>>>(cnt_buf, block_offs, row_ptr, cursor, N, E);
    scatter_kernel<<<eb, 256, 0, stream>>>(src, dst, cursor, edge_src, E);

    node_gather<<<(N + 3) / 4, 256, 0, stream>>>(AB, row_ptr, edge_src, c_bf, N);

    node_apply_mfma<<<gb, 256, 0, stream>>>(h, c_bf, Wn_t, bn, (float*)d_out, N);
}

// Round 13
// 324.806 us; speedup vs baseline: 1.0107x; 1.0107x over previous
//
#include <hip/hip_runtime.h>

#define D 128
#define SCAN_EPB 1024   // counters per scan block (256 threads x int4)

typedef float f32x4 __attribute__((ext_vector_type(4)));
typedef short s16x8 __attribute__((ext_vector_type(8)));

__device__ __forceinline__ unsigned short f2bf(float f) {
    union { float f; unsigned u; } v; v.f = f;
    unsigned r = v.u + 0x7FFF + ((v.u >> 16) & 1);   // RNE
    return (unsigned short)(r >> 16);
}
__device__ __forceinline__ float bf2f(unsigned short u) {
    union { unsigned u; float f; } v; v.u = (unsigned)u << 16;
    return v.f;
}
__device__ __forceinline__ s16x8 pack2(float4 lo, float4 hi) {
    s16x8 o;
    o[0] = (short)f2bf(lo.x); o[1] = (short)f2bf(lo.y);
    o[2] = (short)f2bf(lo.z); o[3] = (short)f2bf(lo.w);
    o[4] = (short)f2bf(hi.x); o[5] = (short)f2bf(hi.y);
    o[6] = (short)f2bf(hi.z); o[7] = (short)f2bf(hi.w);
    return o;
}

// ---------------------------------------------------------------------------
// Prep: transpose weights to [col][k] bf16 once; fuse biases of A|B.
// ---------------------------------------------------------------------------
__launch_bounds__(256)
__global__ void prep_weights(const float* __restrict__ WA, const float* __restrict__ bA,
                             const float* __restrict__ WB, const float* __restrict__ bB,
                             const float* __restrict__ Wn,
                             short* __restrict__ Wab_t, short* __restrict__ Wn_t,
                             float* __restrict__ bias_ab)
{
    const int b = blockIdx.x, t = threadIdx.x;
    if (b < 256) {                                   // Wab_t col b, K=128
        if (t < 128)
            Wab_t[b * 128 + t] = (short)f2bf(b < 128 ? WA[t * 128 + b]
                                                     : WB[t * 128 + (b - 128)]);
        if (t == 128) bias_ab[b] = (b < 128) ? bA[b] : bB[b - 128];
    } else {                                         // Wn_t col (b-256), K=256
        const int col = b - 256;
        Wn_t[col * 256 + t] = (short)f2bf(Wn[t * 128 + col]);
    }
}

// ---------------------------------------------------------------------------
// Kernel 1: bf16 MFMA GEMM producing interleaved AE4 rows:
// group j (4 shorts): [a_{2j}, a_{2j+1}, E_{2j}, E_{2j+1}] where a = h@WA+bA
// and E = exp(-(h@WB+bB)).  sigmoid(bs+bd) = 1/(1 + Es*Ed), so node_gather
// needs NO per-edge exp — just fma+rcp.  One dwordx2 per edge per lane.
// ---------------------------------------------------------------------------
__launch_bounds__(256)
__global__ void gemm_ab_mfma(const float* __restrict__ h,
                             const short* __restrict__ Wab_t,
                             const float* __restrict__ bias_ab,
                             short* __restrict__ AB, int N)
{
    const int tid = threadIdx.x, w = tid >> 6, l = tid & 63;
    const int rbase = blockIdx.x * 64 + w * 16;
    if (rbase >= N) return;                          // N%16==0: waves all-or-nothing
    const int g = l >> 4, r = l & 15;

    const float* hrow = h + (size_t)(rbase + r) * D + g * 8;
    s16x8 af[4];
    #pragma unroll
    for (int s = 0; s < 4; ++s) {
        float4 lo = *(const float4*)(hrow + s * 32);
        float4 hi = *(const float4*)(hrow + s * 32 + 4);
        af[s] = pack2(lo, hi);
    }

    f32x4 acc[16];
    #pragma unroll
    for (int t = 0; t < 16; ++t) acc[t] = (f32x4){0.f, 0.f, 0.f, 0.f};

    #pragma unroll
    for (int t = 0; t < 16; ++t) {
        const short* wc = Wab_t + (size_t)(t * 16 + r) * 128 + g * 8;
        #pragma unroll
        for (int s = 0; s < 4; ++s) {
            s16x8 bf = *(const s16x8*)(wc + s * 32);
            acc[t] = __builtin_amdgcn_mfma_f32_16x16x32_bf16(af[s], bf, acc[t], 0, 0, 0);
        }
    }

    #pragma unroll
    for (int t = 0; t < 16; ++t) {
        const int col = t * 16 + r;
        const int f   = col & 127;
        const int pos = ((f >> 1) << 2) + (f & 1) + ((t < 8) ? 0 : 2);
        const float bb = bias_ab[col];
        #pragma unroll
        for (int q = 0; q < 4; ++q) {
            const int orow = rbase + g * 4 + q;
            float x = acc[t][q] + bb;
            if (t >= 8) x = __expf(-x);              // E = exp(-b), uniform per t
            AB[(size_t)orow * 256 + pos] = (short)f2bf(x);
        }
    }
}

// ---------------------------------------------------------------------------
// CSR build: histogram -> 3-pass multi-block exclusive scan -> scatter
// ---------------------------------------------------------------------------
__launch_bounds__(256)
__global__ void hist_kernel(const int* __restrict__ dst,
                            int* __restrict__ counters, int E)
{
    const int e = blockIdx.x * 256 + threadIdx.x;
    if (e < E) atomicAdd(&counters[dst[e]], 1);
}

__launch_bounds__(256)
__global__ void scan_pass1(const int* __restrict__ counters,
                           int* __restrict__ block_sums, int N)
{
    const int b = blockIdx.x, t = threadIdx.x;
    const int base = b * SCAN_EPB + t * 4;
    int s = 0;
    if (base + 3 < N) {
        const int4 v = *(const int4*)&counters[base];
        s = v.x + v.y + v.z + v.w;
    } else {
        #pragma unroll
        for (int i = 0; i < 4; ++i) if (base + i < N) s += counters[base + i];
    }
    #pragma unroll
    for (int off = 32; off >= 1; off >>= 1) s += __shfl_xor(s, off);
    __shared__ int ws[4];
    const int wave = t >> 6, lane = t & 63;
    if (lane == 0) ws[wave] = s;
    __syncthreads();
    if (t == 0) block_sums[b] = ws[0] + ws[1] + ws[2] + ws[3];
}

__launch_bounds__(1024)
__global__ void scan_pass2(const int* __restrict__ block_sums,
                           int* __restrict__ block_offs, int NB)
{
    __shared__ int part[1024];
    const int t = threadIdx.x;
    part[t] = (t < NB) ? block_sums[t] : 0;
    __syncthreads();
    for (int off = 1; off < 1024; off <<= 1) {
        int v = (t >= off) ? part[t - off] : 0;
        __syncthreads();
        part[t] += v;
        __syncthreads();
    }
    if (t < NB) block_offs[t] = (t == 0) ? 0 : part[t - 1];
}

__launch_bounds__(256)
__global__ void scan_pass3(const int* __restrict__ counters,
                           const int* __restrict__ block_offs,
                           int* __restrict__ row_ptr, int* __restrict__ cursor,
                           int N, int E)
{
    const int b = blockIdx.x, t = threadIdx.x;
    const int wave = t >> 6, lane = t & 63;
    const int base = b * SCAN_EPB + t * 4;

    int4 v = make_int4(0, 0, 0, 0);
    if (base + 3 < N) {
        v = *(const int4*)&counters[base];
    } else {
        if (base + 0 < N) v.x = counters[base + 0];
        if (base + 1 < N) v.y = counters[base + 1];
        if (base + 2 < N) v.z = counters[base + 2];
        if (base + 3 < N) v.w = counters[base + 3];
    }
    const int tsum = v.x + v.y + v.z + v.w;

    int x = tsum;
    #pragma unroll
    for (int off = 1; off < 64; off <<= 1) {
        int y = __shfl_up(x, off);
        if (lane >= off) x += y;
    }
    __shared__ int wsum[4];
    if (lane == 63) wsum[wave] = x;
    __syncthreads();
    int woff = 0;
    #pragma unroll
    for (int w = 0; w < 4; ++w) woff += (w < wave) ? wsum[w] : 0;

    const int p0 = block_offs[b] + woff + (x - tsum);
    const int p1 = p0 + v.x;
    const int p2 = p1 + v.y;
    const int p3 = p2 + v.z;
    if (base + 0 < N) { row_ptr[base + 0] = p0; cursor[base + 0] = p0; }
    if (base + 1 < N) { row_ptr[base + 1] = p1; cursor[base + 1] = p1; }
    if (base + 2 < N) { row_ptr[base + 2] = p2; cursor[base + 2] = p2; }
    if (base + 3 < N) { row_ptr[base + 3] = p3; cursor[base + 3] = p3; }
    if (b == 0 && t == 0) row_ptr[N] = E;
}

__launch_bounds__(256)
__global__ void scatter_kernel(const int* __restrict__ src,
                               const int* __restrict__ dst,
                               int* __restrict__ cursor,
                               int* __restrict__ edge_src, int E)
{
    const int e = blockIdx.x * 256 + threadIdx.x;
    if (e < E) {
        const int pos = atomicAdd(&cursor[dst[e]], 1);
        edge_src[pos] = src[e];
    }
}

// ---------------------------------------------------------------------------
// Kernel 2: per-dst-node gather + gated-message max-reduce (interleaved AE4).
// Factorized sigmoid: p = a * rcp(1 + Es*Ed). Per edge per lane: 1 dwordx2
// load, 2 unpack, 2 fma, 2 rcp, 2 mul, 2 max — NO exp. 4-edge unroll, 4
// independent max chains. m init 0 = relu + zero-in-degree clamp.
// ---------------------------------------------------------------------------
__device__ __forceinline__ void edge_step(const short* __restrict__ AB, int s,
                                          unsigned lofs8, float Ed0, float Ed1,
                                          float& m0, float& m1)
{
    const short* rowp = AB + ((size_t)s << 8);
    const uint2 v = *(const uint2*)((const char*)rowp + lofs8);
    const float den0 = fmaf(__uint_as_float(v.y << 16), Ed0, 1.f);
    const float den1 = fmaf(__uint_as_float(v.y & 0xFFFF0000u), Ed1, 1.f);
    const float p0 = __fdividef(__uint_as_float(v.x << 16), den0);
    const float p1 = __fdividef(__uint_as_float(v.x & 0xFFFF0000u), den1);
    m0 = fmaxf(m0, p0);
    m1 = fmaxf(m1, p1);
}

__launch_bounds__(256)
__global__ void node_gather(const short* __restrict__ AB,
                            const int* __restrict__ row_ptr,
                            const int* __restrict__ edge_src,
                            short* __restrict__ c, int N)
{
    const int wave = threadIdx.x >> 6, lane = threadIdx.x & 63;
    const int d = blockIdx.x * 4 + wave;
    if (d >= N) return;

    const int beg = __builtin_amdgcn_readfirstlane(row_ptr[d]);
    const int end = __builtin_amdgcn_readfirstlane(row_ptr[d + 1]);
    const unsigned lofs8 = (unsigned)lane * 8;       // byte offset of group j=lane

    // dst E-pair: dword at byte offset lane*8 + 4 of row d
    const unsigned edp = *(const unsigned*)((const char*)(AB + ((size_t)d << 8)) + lofs8 + 4);
    const float Ed0 = __uint_as_float(edp << 16);
    const float Ed1 = __uint_as_float(edp & 0xFFFF0000u);

    float m0a = 0.f, m1a = 0.f, m0b = 0.f, m1b = 0.f;
    float m0c = 0.f, m1c = 0.f, m0d = 0.f, m1d = 0.f;

    int i = beg;
    for (; i + 4 <= end; i += 4) {
        const int s0 = __builtin_amdgcn_readfirstlane(edge_src[i]);
        const int s1 = __builtin_amdgcn_readfirstlane(edge_src[i + 1]);
        const int s2 = __builtin_amdgcn_readfirstlane(edge_src[i + 2]);
        const int s3 = __builtin_amdgcn_readfirstlane(edge_src[i + 3]);
        edge_step(AB, s0, lofs8, Ed0, Ed1, m0a, m1a);
        edge_step(AB, s1, lofs8, Ed0, Ed1, m0b, m1b);
        edge_step(AB, s2, lofs8, Ed0, Ed1, m0c, m1c);
        edge_step(AB, s3, lofs8, Ed0, Ed1, m0d, m1d);
    }
    for (; i < end; ++i) {
        const int s = __builtin_amdgcn_readfirstlane(edge_src[i]);
        edge_step(AB, s, lofs8, Ed0, Ed1, m0a, m1a);
    }

    const float m0 = fmaxf(fmaxf(m0a, m0b), fmaxf(m0c, m0d));
    const float m1 = fmaxf(fmaxf(m1a, m1b), fmaxf(m1c, m1d));
    const unsigned packed = (unsigned)f2bf(m0) | ((unsigned)f2bf(m1) << 16);
    *(unsigned*)&c[(size_t)d * D + lane * 2] = packed;
}

// ---------------------------------------------------------------------------
// Kernel 3: bundle = [h|c]@Wn + bn (bf16 MFMA, K=256); L2-norm; relu; residual.
// ---------------------------------------------------------------------------
__launch_bounds__(256)
__global__ void node_apply_mfma(const float* __restrict__ h,
                                const short* __restrict__ c,
                                const short* __restrict__ Wn_t,
                                const float* __restrict__ bn,
                                float* __restrict__ out, int N)
{
    const int tid = threadIdx.x, w = tid >> 6, l = tid & 63;
    const int rbase = blockIdx.x * 64 + w * 16;
    if (rbase >= N) return;
    const int g = l >> 4, r = l & 15;

    const float* hrow = h + (size_t)(rbase + r) * D + g * 8;
    const short* crow = c + (size_t)(rbase + r) * D + g * 8;

    f32x4 acc[8];
    #pragma unroll
    for (int t = 0; t < 8; ++t) acc[t] = (f32x4){0.f, 0.f, 0.f, 0.f};

    #pragma unroll
    for (int s = 0; s < 8; ++s) {
        s16x8 af;
        if (s < 4) {
            float4 lo = *(const float4*)(hrow + s * 32);
            float4 hi = *(const float4*)(hrow + s * 32 + 4);
            af = pack2(lo, hi);
        } else {
            af = *(const s16x8*)(crow + (s - 4) * 32);
        }
        #pragma unroll
        for (int t = 0; t < 8; ++t) {
            s16x8 bf = *(const s16x8*)(Wn_t + (size_t)(t * 16 + r) * 256 + s * 32 + g * 8);
            acc[t] = __builtin_amdgcn_mfma_f32_16x16x32_bf16(af, bf, acc[t], 0, 0, 0);
        }
    }

    float v[8][4];
    float ss[4] = {0.f, 0.f, 0.f, 0.f};
    #pragma unroll
    for (int t = 0; t < 8; ++t) {
        const float bb = bn[t * 16 + r];
        #pragma unroll
        for (int q = 0; q < 4; ++q) {
            const float x = acc[t][q] + bb;
            v[t][q] = x;
            ss[q] += x * x;
        }
    }
    #pragma unroll
    for (int m = 1; m < 16; m <<= 1) {      // reduce across the 16 lanes of a group
        #pragma unroll
        for (int q = 0; q < 4; ++q) ss[q] += __shfl_xor(ss[q], m);
    }
    float inv[4];
    #pragma unroll
    for (int q = 0; q < 4; ++q) inv[q] = 1.0f / fmaxf(sqrtf(ss[q]), 1e-12f);

    #pragma unroll
    for (int t = 0; t < 8; ++t) {
        const int col = t * 16 + r;
        #pragma unroll
        for (int q = 0; q < 4; ++q) {
            const size_t o = (size_t)(rbase + g * 4 + q) * D + col;
            out[o] = h[o] + fmaxf(v[t][q] * inv[q], 0.0f);
        }
    }
}

// ---------------------------------------------------------------------------
extern "C" void kernel_launch(void* const* d_in, const int* in_sizes, int n_in,
                              void* d_out, int out_size, void* d_ws, size_t ws_size,
                              hipStream_t stream)
{
    const float* h   = (const float*)d_in[0];
    const int*   src = (const int*)  d_in[1];
    const int*   dst = (const int*)  d_in[2];
    const float* WA  = (const float*)d_in[3];
    const float* bA  = (const float*)d_in[4];
    const float* WB  = (const float*)d_in[5];
    const float* bB  = (const float*)d_in[6];
    const float* Wn  = (const float*)d_in[7];
    const float* bn  = (const float*)d_in[8];

    const int N = in_sizes[0] / D;
    const int E = in_sizes[1];

    // workspace layout (~42 MB; rounds 6-7 prove ws >= ~55 MB)
    const size_t npad = (size_t)((N + 4 + 3) / 4) * 4;
    const size_t n4   = (size_t)((N + 3) / 4) * 4;
    short* AB         = (short*)d_ws;                 // [N][256] bf16, AE4 interleaved
    short* c_bf       = AB + (size_t)N * 256;         // [N][128] bf16
    short* Wab_t      = c_bf + (size_t)N * D;         // [256][128] bf16
    short* Wn_t       = Wab_t + 256 * 128;            // [128][256] bf16
    float* bias_ab    = (float*)(Wn_t + 128 * 256);   // [256]
    int*   row_ptr    = (int*)(bias_ab + 256);
    int*   cursor     = row_ptr + npad;
    int*   cnt_buf    = cursor + n4;
    int*   block_sums = cnt_buf + n4;
    int*   block_offs = block_sums + 1024;
    int*   edge_src   = block_offs + 1024;

    hipMemsetAsync(cnt_buf, 0, (size_t)N * sizeof(int), stream);

    prep_weights<<<384, 256, 0, stream>>>(WA, bA, WB, bB, Wn, Wab_t, Wn_t, bias_ab);

    const int gb = (N + 63) / 64;
    gemm_ab_mfma<<<gb, 256, 0, stream>>>(h, Wab_t, bias_ab, AB, N);

    const int eb = (E + 255) / 256;
    const int NB = (N + SCAN_EPB - 1) / SCAN_EPB;
    hist_kernel<<<eb, 256, 0, stream>>>(dst, cnt_buf, E);
    scan_pass1<<<NB, 256, 0, stream>>>(cnt_buf, block_sums, N);
    scan_pass2<<<1, 1024, 0, stream>>>(block_sums, block_offs, NB);
    scan_pass3<<<NB, 256, 0, stream>>>(cnt_buf, block_offs, row_ptr, cursor, N, E);
    scatter_kernel<<<eb, 256, 0, stream>>>(src, dst, cursor, edge_src, E);

    node_gather<<<(N + 3) / 4, 256, 0, stream>>>(AB, row_ptr, edge_src, c_bf, N);

    node_apply_mfma<<<gb, 256, 0, stream>>>(h, c_bf, Wn_t, bn, (float*)d_out, N);
}